// Round 10
// baseline (251.227 us; speedup 1.0000x reference)
//
#include <hip/hip_runtime.h>
#include <math.h>

// Problem constants: B=2, N=2048, C=1024, H=16, d=64
constexpr int Bc = 2;
constexpr int Nc = 2048;
constexpr int Cc = 1024;
constexpr int Hc = 16;
constexpr int Dc = 64;

typedef __bf16 bf16x8 __attribute__((ext_vector_type(8)));
typedef __bf16 bf16x4 __attribute__((ext_vector_type(4)));
typedef float  f32x4  __attribute__((ext_vector_type(4)));

// async global->LDS, 16 B per lane; LDS dest = uniform base + lane*16
__device__ __forceinline__ void gload_lds16(const __bf16* g, __bf16* l) {
    __builtin_amdgcn_global_load_lds(
        (const __attribute__((address_space(1))) void*)g,
        (__attribute__((address_space(3))) void*)l, 16, 0, 0);
}

#define MFMA16(A, B, C) __builtin_amdgcn_mfma_f32_16x16x32_bf16(A, B, C, 0, 0, 0)

#if __has_builtin(__builtin_amdgcn_exp2f)
#define EXP2F(x) __builtin_amdgcn_exp2f(x)
#else
#define EXP2F(x) exp2f(x)
#endif

// 0.125 (1/sqrt(64)) * log2(e): folded into q so softmax exp is one v_exp_f32
#define QSCALE 0.18033688011112042f

// ---------------------------------------------------------------------------
// prologue: one launch doing rope tables + all input packs (block-range
// dispatch; each section is whole blocks so no divergence).
//   blocks [0,256):      rope tables (fp64 for fidelity)
//   blocks [256,4352):   x -> Xh bf16 (pack_h)
//   blocks [4352,5120):  w_qkv [K][3072] -> Wqh^T [3072][K] bf16
//   blocks [5120,5376):  w_proj [K][1024] -> Wph/Wpl^T hi/lo (Markidis split)
// ---------------------------------------------------------------------------
__global__ __launch_bounds__(256) void prologue(
    const float* __restrict__ x, const float* __restrict__ w_qkv,
    const float* __restrict__ w_proj,
    float* __restrict__ cosT, float* __restrict__ sinT,
    __bf16* __restrict__ Xh, __bf16* __restrict__ Wqh,
    __bf16* __restrict__ Wph, __bf16* __restrict__ Wpl) {
    __shared__ float t[64][65];
    const int blk = blockIdx.x;
    const int tid = threadIdx.x;

    if (blk < 256) {                       // --- rope tables ---
        int idx = blk * 256 + tid;         // N*32 = 65536
        int n = idx >> 5, j = idx & 31;
        double inv = pow(10000.0, -(double)j / 32.0);
        double ang = (double)n * inv;
        cosT[idx] = (float)cos(ang);
        sinT[idx] = (float)sin(ang);
    } else if (blk < 4352) {               // --- pack x -> bf16 ---
        int i = (blk - 256) * 256 + tid;   // HS/4 float4s
        float4 v = ((const float4*)x)[i];
        bf16x4 hv = {(__bf16)v.x, (__bf16)v.y, (__bf16)v.z, (__bf16)v.w};
        ((bf16x4*)Xh)[i] = hv;
    } else if (blk < 5120) {               // --- w_qkv transpose, hi only ---
        constexpr int K = 1024, Nn = 3072;
        int lin = blk - 4352;
        int n0 = (lin % 48) * 64, k0 = (lin / 48) * 64;
        int c = tid & 63, r4 = tid >> 6;
        #pragma unroll 4
        for (int p = 0; p < 16; ++p) {
            int kr = p * 4 + r4;
            t[c][kr] = w_qkv[(size_t)(k0 + kr) * Nn + n0 + c];
        }
        __syncthreads();
        #pragma unroll 4
        for (int p = 0; p < 16; ++p) {
            int nr = p * 4 + r4;
            Wqh[(size_t)(n0 + nr) * K + k0 + c] = (__bf16)t[nr][c];
        }
    } else {                               // --- w_proj transpose, hi/lo ---
        constexpr int K = 1024, Nn = 1024;
        int lin = blk - 5120;
        int n0 = (lin & 15) * 64, k0 = (lin >> 4) * 64;
        int c = tid & 63, r4 = tid >> 6;
        #pragma unroll 4
        for (int p = 0; p < 16; ++p) {
            int kr = p * 4 + r4;
            t[c][kr] = w_proj[(size_t)(k0 + kr) * Nn + n0 + c];
        }
        __syncthreads();
        #pragma unroll 4
        for (int p = 0; p < 16; ++p) {
            int nr = p * 4 + r4;
            float v = t[nr][c];
            __bf16 hi = (__bf16)v;
            size_t o = (size_t)(n0 + nr) * K + k0 + c;
            Wph[o] = hi;
            Wpl[o] = (__bf16)(v - (float)hi);
        }
    }
}

// ---------------------------------------------------------------------------
// gemm_qkv_bf: pure-bf16 MFMA GEMM (4096x3072x1024) with fused epilogue.
//  - q: RoPE + QSCALE (1/8 * log2e, enables exp2 softmax) -> Qh
//  - k: RoPE -> Kh
//  - v: transpose -> Vt [bh][64][N]
// Epilogue routed through per-wave LDS (stride 72) -> 16B coalesced stores.
// ---------------------------------------------------------------------------
__global__ __launch_bounds__(256) void gemm_qkv_bf(
    const __bf16* __restrict__ Xh, const __bf16* __restrict__ Wh,
    const float* __restrict__ cosT, const float* __restrict__ sinT,
    __bf16* __restrict__ Qh, __bf16* __restrict__ Kh,
    __bf16* __restrict__ Vt) {
    constexpr int K = 1024;
    __shared__ __bf16 sm[18432];       // 36 KB

    const int w = threadIdx.x >> 6;
    const int lane = threadIdx.x & 63;
    const int l16 = lane & 15, quad = lane >> 4;
    const int row0 = blockIdx.y * 128;
    const int col0 = blockIdx.x * 128;
    const int wr = (w >> 1) * 64, wc = (w & 1) * 64;
    const int srow = lane & 15, soct = lane >> 4;

    f32x4 acc[4][4];
    #pragma unroll
    for (int mi = 0; mi < 4; ++mi)
        #pragma unroll
        for (int ni = 0; ni < 4; ++ni) acc[mi][ni] = (f32x4){0.f, 0.f, 0.f, 0.f};

    for (int k0 = 0; k0 < K; k0 += 32) {
        __syncthreads();
        #pragma unroll
        for (int i = 0; i < 4; ++i) {
            int c = i * 4 + w;            // 0..15
            int arr = c >> 3, t = c & 7;
            const __bf16* src = (arr == 0)
                ? Xh + (size_t)(row0 + t * 16 + srow) * K
                : Wh + (size_t)(col0 + t * 16 + srow) * K;
            gload_lds16(src + k0 + soct * 8, &sm[arr * 4096 + t * 512]);
        }
        __syncthreads();

        bf16x8 a[4], b[4];
        #pragma unroll
        for (int i = 0; i < 4; ++i) {
            a[i] = *(const bf16x8*)&sm[(wr / 16 + i) * 512 + quad * 128 + l16 * 8];
            b[i] = *(const bf16x8*)&sm[4096 + (wc / 16 + i) * 512 + quad * 128 + l16 * 8];
        }
        #pragma unroll
        for (int mi = 0; mi < 4; ++mi)
            #pragma unroll
            for (int ni = 0; ni < 4; ++ni)
                acc[mi][ni] = MFMA16(a[mi], b[ni], acc[mi][ni]);
    }

    __syncthreads();                     // staging region free; reuse for epilogue
    __bf16* T = &sm[w * 4608];           // per-wave 64x72

    const int gcol0 = col0 + wc;
    const int region = gcol0 >> 10;      // 0=q, 1=k, 2=v
    const int h = (gcol0 & 1023) >> 6;
    const int rb = row0 + wr;
    const int bq = rb >> 11;
    const int nb = rb & 2047;
    const int bh_ = bq * Hc + h;

    if (region < 2) {
        const float scl = (region == 0) ? QSCALE : 1.f;
        #pragma unroll
        for (int mi = 0; mi < 4; ++mi)
            #pragma unroll
            for (int r = 0; r < 4; ++r) {
                int nn = mi * 16 + quad * 4 + r;
                int n = nb + nn;
                float c1 = cosT[n * 32 + l16],      s1 = sinT[n * 32 + l16];
                float c2 = cosT[n * 32 + 16 + l16], s2 = sinT[n * 32 + 16 + l16];
                float x1 = acc[mi][0][r], x2 = acc[mi][2][r];
                float a0 = (x1 * c1 - x2 * s1) * scl;
                float b0 = (x1 * s1 + x2 * c1) * scl;
                x1 = acc[mi][1][r]; x2 = acc[mi][3][r];
                float a1 = (x1 * c2 - x2 * s2) * scl;
                float b1 = (x1 * s2 + x2 * c2) * scl;
                T[nn * 72 + l16]      = (__bf16)a0;
                T[nn * 72 + 16 + l16] = (__bf16)a1;
                T[nn * 72 + 32 + l16] = (__bf16)b0;
                T[nn * 72 + 48 + l16] = (__bf16)b1;
            }
        asm volatile("s_waitcnt lgkmcnt(0)" ::: "memory");   // wave-local RAW
        __bf16* Dst = ((region == 0) ? Qh : Kh) + (size_t)bh_ * Nc * Dc;
        #pragma unroll
        for (int p = 0; p < 8; ++p) {
            int n = p * 8 + (lane >> 3);
            int d8 = (lane & 7) * 8;
            bf16x8 v = *(const bf16x8*)&T[n * 72 + d8];
            *(bf16x8*)(Dst + (size_t)(nb + n) * Dc + d8) = v;
        }
    } else {
        #pragma unroll
        for (int mi = 0; mi < 4; ++mi)
            #pragma unroll
            for (int ni = 0; ni < 4; ++ni)
                #pragma unroll
                for (int r = 0; r < 4; ++r)
                    T[(ni * 16 + l16) * 72 + mi * 16 + quad * 4 + r]
                        = (__bf16)acc[mi][ni][r];
        asm volatile("s_waitcnt lgkmcnt(0)" ::: "memory");
        #pragma unroll
        for (int p = 0; p < 8; ++p) {
            int d = p * 8 + (lane >> 3);
            int n8 = (lane & 7) * 8;
            bf16x8 v = *(const bf16x8*)&T[d * 72 + n8];
            *(bf16x8*)(Vt + ((size_t)bh_ * Dc + d) * Nc + nb + n8) = v;
        }
    }
}

// ---------------------------------------------------------------------------
// gemm_proj: split-bf16 (Markidis) GEMM, 64x128 tile — proj errors hit the
// output directly, so keeps fp32-grade accuracy.
// ---------------------------------------------------------------------------
__global__ __launch_bounds__(256) void gemm_proj(
    const __bf16* __restrict__ Ah, const __bf16* __restrict__ Al,
    const __bf16* __restrict__ Bh, const __bf16* __restrict__ Bl,
    const float* __restrict__ bias, float* __restrict__ C,
    int M, int N, int K) {
    __shared__ __bf16 lds[24 * 512];   // [Ah:0-3][Al:4-7][Bh:8-15][Bl:16-23]

    const int w = threadIdx.x >> 6;
    const int lane = threadIdx.x & 63;
    const int l16 = lane & 15, quad = lane >> 4;
    const int row0 = blockIdx.y * 64;
    const int col0 = blockIdx.x * 128;
    const int wr = (w >> 1) * 32, wc = (w & 1) * 64;
    const int srow = lane & 15, soct = lane >> 4;

    f32x4 acc[2][4];
    #pragma unroll
    for (int mi = 0; mi < 2; ++mi)
        #pragma unroll
        for (int ni = 0; ni < 4; ++ni) acc[mi][ni] = (f32x4){0.f, 0.f, 0.f, 0.f};

    for (int k0 = 0; k0 < K; k0 += 32) {
        __syncthreads();
        #pragma unroll
        for (int r = 0; r < 6; ++r) {
            int c = r * 4 + w;
            const __bf16* src;
            if (c < 4)       src = Ah + (size_t)(row0 + c * 16 + srow) * K;
            else if (c < 8)  src = Al + (size_t)(row0 + (c - 4) * 16 + srow) * K;
            else if (c < 16) src = Bh + (size_t)(col0 + (c - 8) * 16 + srow) * K;
            else             src = Bl + (size_t)(col0 + (c - 16) * 16 + srow) * K;
            gload_lds16(src + k0 + soct * 8, &lds[c * 512]);
        }
        __syncthreads();

        bf16x8 ah[2], al[2], bh[4], bl[4];
        #pragma unroll
        for (int mi = 0; mi < 2; ++mi) {
            int ia = (wr / 16 + mi) * 512 + quad * 128 + l16 * 8;
            ah[mi] = *(const bf16x8*)&lds[ia];
            al[mi] = *(const bf16x8*)&lds[4 * 512 + ia];
        }
        #pragma unroll
        for (int ni = 0; ni < 4; ++ni) {
            int ib = (wc / 16 + ni) * 512 + quad * 128 + l16 * 8;
            bh[ni] = *(const bf16x8*)&lds[8 * 512 + ib];
            bl[ni] = *(const bf16x8*)&lds[16 * 512 + ib];
        }
        #pragma unroll
        for (int mi = 0; mi < 2; ++mi)
            #pragma unroll
            for (int ni = 0; ni < 4; ++ni) {
                acc[mi][ni] = MFMA16(ah[mi], bl[ni], acc[mi][ni]);
                acc[mi][ni] = MFMA16(al[mi], bh[ni], acc[mi][ni]);
                acc[mi][ni] = MFMA16(ah[mi], bh[ni], acc[mi][ni]);
            }
    }

    #pragma unroll
    for (int mi = 0; mi < 2; ++mi)
        #pragma unroll
        for (int ni = 0; ni < 4; ++ni) {
            int col = col0 + wc + ni * 16 + l16;
            float bv = bias ? bias[col] : 0.f;
            #pragma unroll
            for (int r = 0; r < 4; ++r) {
                int row = row0 + wr + mi * 16 + quad * 4 + r;
                C[(size_t)row * N + col] = acc[mi][ni][r] + bv;
            }
        }
}

// ---------------------------------------------------------------------------
// attn_mfma: bf16 QK + bf16 PV, no-max softmax via exp2 (log2e pre-folded
// into q), l computed by a ones-B-fragment MFMA (P·1 = row sums, replicated
// across lanes -> no VALU accumulation, no epilogue shuffles).
// mi=2 ILP, LDS-staged Kh/Vt, grid split-K x2 with add-merge.
// ---------------------------------------------------------------------------
__global__ __launch_bounds__(256) void attn_mfma(
    const __bf16* __restrict__ Qh, const __bf16* __restrict__ Kh,
    const __bf16* __restrict__ Vt,
    float* __restrict__ Opart, float* __restrict__ lpart) {
    const int bh = blockIdx.y;
    const int sp = blockIdx.z;
    const int q0 = blockIdx.x * 128;
    const int w = threadIdx.x >> 6;
    const int lane = threadIdx.x & 63;
    const int l16 = lane & 15, quad = lane >> 4;

    const __bf16* Qhb = Qh + (size_t)bh * Nc * Dc;
    const __bf16* Khb = Kh + (size_t)bh * Nc * Dc;
    const __bf16* Vtb = Vt + (size_t)bh * Dc * Nc;

    bf16x8 qh[2][2];
    #pragma unroll
    for (int mi = 0; mi < 2; ++mi)
        #pragma unroll
        for (int ks = 0; ks < 2; ++ks)
            qh[mi][ks] = *(const bf16x8*)(Qhb
                + (size_t)(q0 + w * 32 + mi * 16 + l16) * Dc + ks * 32 + quad * 8);

    const __bf16 one = (__bf16)1.0f;
    const bf16x8 onesb = {one, one, one, one, one, one, one, one};

    f32x4 Oa[2][4], Ol[2];
    #pragma unroll
    for (int mi = 0; mi < 2; ++mi) {
        #pragma unroll
        for (int ni = 0; ni < 4; ++ni) Oa[mi][ni] = (f32x4){0.f, 0.f, 0.f, 0.f};
        Ol[mi] = (f32x4){0.f, 0.f, 0.f, 0.f};
    }

    __shared__ __bf16 smT[2][4096];       // Kh, Vt tiles (16 KB)
    __shared__ __bf16 Plds[4][32 * 72];   // per-wave P (18 KB)
    __bf16* Pw = Plds[w];

    const int srow = lane & 15;
    const int soct = lane >> 4;

    for (int tile = 0; tile < 16; ++tile) {
        const int kt0 = sp * 1024 + tile * 64;
        __syncthreads();
        #pragma unroll
        for (int i = 0; i < 4; ++i) {
            int c = i * 4 + w;
            int arr = c >> 3, t = c & 7, g = t >> 1, half = t & 1;
            const __bf16* src = (arr == 0)
                ? Khb + (size_t)(kt0 + 16 * g + srow) * Dc + half * 32 + soct * 8
                : Vtb + (size_t)(16 * g + srow) * Nc + kt0 + half * 32 + soct * 8;
            gload_lds16(src, &smT[arr][t * 512]);
        }
        __syncthreads();

        f32x4 S[2][4];
        #pragma unroll
        for (int mi = 0; mi < 2; ++mi)
            #pragma unroll
            for (int kt = 0; kt < 4; ++kt) S[mi][kt] = (f32x4){0.f, 0.f, 0.f, 0.f};

        #pragma unroll
        for (int kt = 0; kt < 4; ++kt) {
            int fb = quad * 128 + l16 * 8;
            bf16x8 kh0 = *(const bf16x8*)&smT[0][(kt * 2 + 0) * 512 + fb];
            bf16x8 kh1 = *(const bf16x8*)&smT[0][(kt * 2 + 1) * 512 + fb];
            #pragma unroll
            for (int mi = 0; mi < 2; ++mi) {
                S[mi][kt] = MFMA16(qh[mi][0], kh0, S[mi][kt]);
                S[mi][kt] = MFMA16(qh[mi][1], kh1, S[mi][kt]);
            }
        }

        // p = 2^s (log2e folded into q); bf16-round; stash for PV
        #pragma unroll
        for (int mi = 0; mi < 2; ++mi)
            #pragma unroll
            for (int kt = 0; kt < 4; ++kt)
                #pragma unroll
                for (int r = 0; r < 4; ++r) {
                    float p = EXP2F(S[mi][kt][r]);
                    Pw[(mi * 16 + quad * 4 + r) * 72 + kt * 16 + l16] = (__bf16)p;
                }

        #pragma unroll
        for (int ks2 = 0; ks2 < 2; ++ks2) {
            bf16x8 Pf[2];
            #pragma unroll
            for (int mi = 0; mi < 2; ++mi)
                Pf[mi] = *(const bf16x8*)&Pw[(mi * 16 + l16) * 72 + ks2 * 32 + quad * 8];
            #pragma unroll
            for (int ni = 0; ni < 4; ++ni) {
                bf16x8 vf = *(const bf16x8*)
                    &smT[1][(ni * 2 + ks2) * 512 + quad * 128 + l16 * 8];
                #pragma unroll
                for (int mi = 0; mi < 2; ++mi)
                    Oa[mi][ni] = MFMA16(Pf[mi], vf, Oa[mi][ni]);
            }
            #pragma unroll
            for (int mi = 0; mi < 2; ++mi)       // l += P . 1 (row sums)
                Ol[mi] = MFMA16(Pf[mi], onesb, Ol[mi]);
        }
    }

    // epilogue: l already per-row in Ol (replicated over l16) — no shuffles
    #pragma unroll
    for (int mi = 0; mi < 2; ++mi)
        #pragma unroll
        for (int r = 0; r < 4; ++r) {
            size_t rowg = (size_t)bh * Nc + q0 + w * 32 + mi * 16 + quad * 4 + r;
            if (l16 == 0) lpart[(size_t)sp * 65536 + rowg] = Ol[mi][r];
            #pragma unroll
            for (int ni = 0; ni < 4; ++ni)
                Opart[((size_t)sp * 65536 + rowg) * Dc + ni * 16 + l16] = Oa[mi][ni][r];
        }
}

// ---------------------------------------------------------------------------
// attn_combine: out = (O0+O1)/(l0+l1), scatter to [B][N][H*D], split hi/lo.
// ---------------------------------------------------------------------------
__global__ __launch_bounds__(256) void attn_combine(
    const float* __restrict__ Opart, const float* __restrict__ lpart,
    __bf16* __restrict__ Aoh, __bf16* __restrict__ Aol) {
    const int t = blockIdx.x * 256 + threadIdx.x;
    const int row = t >> 4, c4 = t & 15;
    const int bh = row >> 11, n = row & 2047;
    const int b = bh >> 4, h = bh & 15;

    float4 v0 = ((const float4*)(Opart + (size_t)row * Dc))[c4];
    float4 v1 = ((const float4*)(Opart + ((size_t)65536 + row) * Dc))[c4];
    float inv = 1.f / (lpart[row] + lpart[65536 + row]);
    float e[4] = {(v0.x + v1.x) * inv, (v0.y + v1.y) * inv,
                  (v0.z + v1.z) * inv, (v0.w + v1.w) * inv};
    size_t off = ((size_t)(b * Nc + n)) * Cc + h * Dc + c4 * 4;
    bf16x4 hv, lv;
    #pragma unroll
    for (int i = 0; i < 4; ++i) {
        __bf16 hi = (__bf16)e[i];
        hv[i] = hi;
        lv[i] = (__bf16)(e[i] - (float)hi);
    }
    *(bf16x4*)(Aoh + off) = hv;
    *(bf16x4*)(Aol + off) = lv;
}

// ---------------------------------------------------------------------------
extern "C" void kernel_launch(void* const* d_in, const int* in_sizes, int n_in,
                              void* d_out, int out_size, void* d_ws, size_t ws_size,
                              hipStream_t stream) {
    const float* x      = (const float*)d_in[0];   // (2,2048,1024)
    const float* w_qkv  = (const float*)d_in[1];   // (1024,3072)
    const float* w_proj = (const float*)d_in[2];   // (1024,1024)
    const float* b_proj = (const float*)d_in[3];   // (1024,)
    float* out = (float*)d_out;                    // (2,2048,1024)

    float* cosT = (float*)d_ws;                        //  65,536 f
    float* sinT = cosT + Nc * 32;                      //  65,536 f
    __bf16* bf = (__bf16*)(sinT + Nc * 32);
    constexpr size_t HS = (size_t)Bc * Hc * Nc * Dc;   // 4,194,304
    __bf16* Qh  = bf;                                  // [BH][N][64]
    __bf16* Kh  = Qh + HS;
    __bf16* Vt  = Kh + HS;                             // [BH][64][N]
    __bf16* Xh  = Vt + HS;                             // x bf16 [4096][1024]
    __bf16* Aoh = Xh;                                  //   (reused after qkv GEMM)
    __bf16* Aol = Xh + HS;
    __bf16* Wqh = Aol + HS;                            // w_qkv^T [3072][1024]
    __bf16* Wph = Wqh + (size_t)3072 * 1024;           // w_proj^T hi
    __bf16* Wpl = Wph + (size_t)1024 * 1024;           // w_proj^T lo
    float* Opart = (float*)(Wpl + (size_t)1024 * 1024);  // 2*65536*64 f
    float* lpart = Opart + (size_t)2 * 65536 * Dc;       // 2*65536 f

    // 1. fused prologue: rope tables + all packs (one launch)
    prologue<<<5376, 256, 0, stream>>>(
        x, w_qkv, w_proj, cosT, sinT, Xh, Wqh, Wph, Wpl);

    // 2. fused qkv GEMM (pure bf16) + RoPE(+log2e fold) + V transpose
    gemm_qkv_bf<<<dim3(3072 / 128, 4096 / 128), 256, 0, stream>>>(
        Xh, Wqh, cosT, sinT, Qh, Kh, Vt);

    // 3. MFMA flash attention, split-K x2 -> unnormalized partials
    attn_mfma<<<dim3(Nc / 128, Bc * Hc, 2), 256, 0, stream>>>(
        Qh, Kh, Vt, Opart, lpart);
    attn_combine<<<(65536 * 16) / 256, 256, 0, stream>>>(
        Opart, lpart, Aoh, Aol);

    // 4. out = attn_out @ w_proj + b_proj  (split-bf16, fp32-grade)
    gemm_proj<<<dim3(1024 / 128, 4096 / 64), 256, 0, stream>>>(
        Aoh, Aol, Wph, Wpl, b_proj, out, 4096, 1024, 1024);
}

// Round 11
// 250.085 us; speedup vs baseline: 1.0046x; 1.0046x over previous
//
#include <hip/hip_runtime.h>
#include <math.h>

// Problem constants: B=2, N=2048, C=1024, H=16, d=64
constexpr int Bc = 2;
constexpr int Nc = 2048;
constexpr int Cc = 1024;
constexpr int Hc = 16;
constexpr int Dc = 64;

typedef __bf16 bf16x8 __attribute__((ext_vector_type(8)));
typedef __bf16 bf16x4 __attribute__((ext_vector_type(4)));
typedef float  f32x4  __attribute__((ext_vector_type(4)));

// async global->LDS, 16 B per lane; LDS dest = uniform base + lane*16
__device__ __forceinline__ void gload_lds16(const __bf16* g, __bf16* l) {
    __builtin_amdgcn_global_load_lds(
        (const __attribute__((address_space(1))) void*)g,
        (__attribute__((address_space(3))) void*)l, 16, 0, 0);
}

#define MFMA16(A, B, C) __builtin_amdgcn_mfma_f32_16x16x32_bf16(A, B, C, 0, 0, 0)

#if __has_builtin(__builtin_amdgcn_exp2f)
#define EXP2F(x) __builtin_amdgcn_exp2f(x)
#else
#define EXP2F(x) exp2f(x)
#endif

// 0.125 (1/sqrt(64)) * log2(e): folded into q so softmax exp is one v_exp_f32
#define QSCALE 0.18033688011112042f

// ---------------------------------------------------------------------------
// prologue: one launch doing rope tables + all input packs (block-range
// dispatch; each section is whole blocks so no divergence).
// ---------------------------------------------------------------------------
__global__ __launch_bounds__(256) void prologue(
    const float* __restrict__ x, const float* __restrict__ w_qkv,
    const float* __restrict__ w_proj,
    float* __restrict__ cosT, float* __restrict__ sinT,
    __bf16* __restrict__ Xh, __bf16* __restrict__ Wqh,
    __bf16* __restrict__ Wph, __bf16* __restrict__ Wpl) {
    __shared__ float t[64][65];
    const int blk = blockIdx.x;
    const int tid = threadIdx.x;

    if (blk < 256) {                       // --- rope tables ---
        int idx = blk * 256 + tid;         // N*32 = 65536
        int n = idx >> 5, j = idx & 31;
        double inv = pow(10000.0, -(double)j / 32.0);
        double ang = (double)n * inv;
        cosT[idx] = (float)cos(ang);
        sinT[idx] = (float)sin(ang);
    } else if (blk < 4352) {               // --- pack x -> bf16 ---
        int i = (blk - 256) * 256 + tid;   // HS/4 float4s
        float4 v = ((const float4*)x)[i];
        bf16x4 hv = {(__bf16)v.x, (__bf16)v.y, (__bf16)v.z, (__bf16)v.w};
        ((bf16x4*)Xh)[i] = hv;
    } else if (blk < 5120) {               // --- w_qkv transpose, hi only ---
        constexpr int K = 1024, Nn = 3072;
        int lin = blk - 4352;
        int n0 = (lin % 48) * 64, k0 = (lin / 48) * 64;
        int c = tid & 63, r4 = tid >> 6;
        #pragma unroll 4
        for (int p = 0; p < 16; ++p) {
            int kr = p * 4 + r4;
            t[c][kr] = w_qkv[(size_t)(k0 + kr) * Nn + n0 + c];
        }
        __syncthreads();
        #pragma unroll 4
        for (int p = 0; p < 16; ++p) {
            int nr = p * 4 + r4;
            Wqh[(size_t)(n0 + nr) * K + k0 + c] = (__bf16)t[nr][c];
        }
    } else {                               // --- w_proj transpose, hi/lo ---
        constexpr int K = 1024, Nn = 1024;
        int lin = blk - 5120;
        int n0 = (lin & 15) * 64, k0 = (lin >> 4) * 64;
        int c = tid & 63, r4 = tid >> 6;
        #pragma unroll 4
        for (int p = 0; p < 16; ++p) {
            int kr = p * 4 + r4;
            t[c][kr] = w_proj[(size_t)(k0 + kr) * Nn + n0 + c];
        }
        __syncthreads();
        #pragma unroll 4
        for (int p = 0; p < 16; ++p) {
            int nr = p * 4 + r4;
            float v = t[nr][c];
            __bf16 hi = (__bf16)v;
            size_t o = (size_t)(n0 + nr) * K + k0 + c;
            Wph[o] = hi;
            Wpl[o] = (__bf16)(v - (float)hi);
        }
    }
}

// ---------------------------------------------------------------------------
// gemm_qkv_bf: pure-bf16 MFMA GEMM (4096x3072x1024) with fused epilogue.
//  - q: RoPE + QSCALE (1/8 * log2e, enables exp2 softmax) -> Qh
//  - k: RoPE -> Kh
//  - v: transpose -> Vt [bh][64][N]
// ---------------------------------------------------------------------------
__global__ __launch_bounds__(256) void gemm_qkv_bf(
    const __bf16* __restrict__ Xh, const __bf16* __restrict__ Wh,
    const float* __restrict__ cosT, const float* __restrict__ sinT,
    __bf16* __restrict__ Qh, __bf16* __restrict__ Kh,
    __bf16* __restrict__ Vt) {
    constexpr int K = 1024;
    __shared__ __bf16 sm[18432];       // 36 KB

    const int w = threadIdx.x >> 6;
    const int lane = threadIdx.x & 63;
    const int l16 = lane & 15, quad = lane >> 4;
    const int row0 = blockIdx.y * 128;
    const int col0 = blockIdx.x * 128;
    const int wr = (w >> 1) * 64, wc = (w & 1) * 64;
    const int srow = lane & 15, soct = lane >> 4;

    f32x4 acc[4][4];
    #pragma unroll
    for (int mi = 0; mi < 4; ++mi)
        #pragma unroll
        for (int ni = 0; ni < 4; ++ni) acc[mi][ni] = (f32x4){0.f, 0.f, 0.f, 0.f};

    for (int k0 = 0; k0 < K; k0 += 32) {
        __syncthreads();
        #pragma unroll
        for (int i = 0; i < 4; ++i) {
            int c = i * 4 + w;            // 0..15
            int arr = c >> 3, t = c & 7;
            const __bf16* src = (arr == 0)
                ? Xh + (size_t)(row0 + t * 16 + srow) * K
                : Wh + (size_t)(col0 + t * 16 + srow) * K;
            gload_lds16(src + k0 + soct * 8, &sm[arr * 4096 + t * 512]);
        }
        __syncthreads();

        bf16x8 a[4], b[4];
        #pragma unroll
        for (int i = 0; i < 4; ++i) {
            a[i] = *(const bf16x8*)&sm[(wr / 16 + i) * 512 + quad * 128 + l16 * 8];
            b[i] = *(const bf16x8*)&sm[4096 + (wc / 16 + i) * 512 + quad * 128 + l16 * 8];
        }
        #pragma unroll
        for (int mi = 0; mi < 4; ++mi)
            #pragma unroll
            for (int ni = 0; ni < 4; ++ni)
                acc[mi][ni] = MFMA16(a[mi], b[ni], acc[mi][ni]);
    }

    __syncthreads();                     // staging region free; reuse for epilogue
    __bf16* T = &sm[w * 4608];           // per-wave 64x72

    const int gcol0 = col0 + wc;
    const int region = gcol0 >> 10;      // 0=q, 1=k, 2=v
    const int h = (gcol0 & 1023) >> 6;
    const int rb = row0 + wr;
    const int bq = rb >> 11;
    const int nb = rb & 2047;
    const int bh_ = bq * Hc + h;

    if (region < 2) {
        const float scl = (region == 0) ? QSCALE : 1.f;
        #pragma unroll
        for (int mi = 0; mi < 4; ++mi)
            #pragma unroll
            for (int r = 0; r < 4; ++r) {
                int nn = mi * 16 + quad * 4 + r;
                int n = nb + nn;
                float c1 = cosT[n * 32 + l16],      s1 = sinT[n * 32 + l16];
                float c2 = cosT[n * 32 + 16 + l16], s2 = sinT[n * 32 + 16 + l16];
                float x1 = acc[mi][0][r], x2 = acc[mi][2][r];
                float a0 = (x1 * c1 - x2 * s1) * scl;
                float b0 = (x1 * s1 + x2 * c1) * scl;
                x1 = acc[mi][1][r]; x2 = acc[mi][3][r];
                float a1 = (x1 * c2 - x2 * s2) * scl;
                float b1 = (x1 * s2 + x2 * c2) * scl;
                T[nn * 72 + l16]      = (__bf16)a0;
                T[nn * 72 + 16 + l16] = (__bf16)a1;
                T[nn * 72 + 32 + l16] = (__bf16)b0;
                T[nn * 72 + 48 + l16] = (__bf16)b1;
            }
        asm volatile("s_waitcnt lgkmcnt(0)" ::: "memory");   // wave-local RAW
        __bf16* Dst = ((region == 0) ? Qh : Kh) + (size_t)bh_ * Nc * Dc;
        #pragma unroll
        for (int p = 0; p < 8; ++p) {
            int n = p * 8 + (lane >> 3);
            int d8 = (lane & 7) * 8;
            bf16x8 v = *(const bf16x8*)&T[n * 72 + d8];
            *(bf16x8*)(Dst + (size_t)(nb + n) * Dc + d8) = v;
        }
    } else {
        #pragma unroll
        for (int mi = 0; mi < 4; ++mi)
            #pragma unroll
            for (int ni = 0; ni < 4; ++ni)
                #pragma unroll
                for (int r = 0; r < 4; ++r)
                    T[(ni * 16 + l16) * 72 + mi * 16 + quad * 4 + r]
                        = (__bf16)acc[mi][ni][r];
        asm volatile("s_waitcnt lgkmcnt(0)" ::: "memory");
        #pragma unroll
        for (int p = 0; p < 8; ++p) {
            int d = p * 8 + (lane >> 3);
            int n8 = (lane & 7) * 8;
            bf16x8 v = *(const bf16x8*)&T[d * 72 + n8];
            *(bf16x8*)(Vt + ((size_t)bh_ * Dc + d) * Nc + nb + n8) = v;
        }
    }
}

// ---------------------------------------------------------------------------
// gemm_proj: split-bf16 (Markidis) GEMM, 64x128 tile — proj errors hit the
// output directly, so keeps fp32-grade accuracy.
// ---------------------------------------------------------------------------
__global__ __launch_bounds__(256) void gemm_proj(
    const __bf16* __restrict__ Ah, const __bf16* __restrict__ Al,
    const __bf16* __restrict__ Bh, const __bf16* __restrict__ Bl,
    const float* __restrict__ bias, float* __restrict__ C,
    int M, int N, int K) {
    __shared__ __bf16 lds[24 * 512];   // [Ah:0-3][Al:4-7][Bh:8-15][Bl:16-23]

    const int w = threadIdx.x >> 6;
    const int lane = threadIdx.x & 63;
    const int l16 = lane & 15, quad = lane >> 4;
    const int row0 = blockIdx.y * 64;
    const int col0 = blockIdx.x * 128;
    const int wr = (w >> 1) * 32, wc = (w & 1) * 64;
    const int srow = lane & 15, soct = lane >> 4;

    f32x4 acc[2][4];
    #pragma unroll
    for (int mi = 0; mi < 2; ++mi)
        #pragma unroll
        for (int ni = 0; ni < 4; ++ni) acc[mi][ni] = (f32x4){0.f, 0.f, 0.f, 0.f};

    for (int k0 = 0; k0 < K; k0 += 32) {
        __syncthreads();
        #pragma unroll
        for (int r = 0; r < 6; ++r) {
            int c = r * 4 + w;
            const __bf16* src;
            if (c < 4)       src = Ah + (size_t)(row0 + c * 16 + srow) * K;
            else if (c < 8)  src = Al + (size_t)(row0 + (c - 4) * 16 + srow) * K;
            else if (c < 16) src = Bh + (size_t)(col0 + (c - 8) * 16 + srow) * K;
            else             src = Bl + (size_t)(col0 + (c - 16) * 16 + srow) * K;
            gload_lds16(src + k0 + soct * 8, &lds[c * 512]);
        }
        __syncthreads();

        bf16x8 ah[2], al[2], bh[4], bl[4];
        #pragma unroll
        for (int mi = 0; mi < 2; ++mi) {
            int ia = (wr / 16 + mi) * 512 + quad * 128 + l16 * 8;
            ah[mi] = *(const bf16x8*)&lds[ia];
            al[mi] = *(const bf16x8*)&lds[4 * 512 + ia];
        }
        #pragma unroll
        for (int ni = 0; ni < 4; ++ni) {
            int ib = (wc / 16 + ni) * 512 + quad * 128 + l16 * 8;
            bh[ni] = *(const bf16x8*)&lds[8 * 512 + ib];
            bl[ni] = *(const bf16x8*)&lds[16 * 512 + ib];
        }
        #pragma unroll
        for (int mi = 0; mi < 2; ++mi)
            #pragma unroll
            for (int ni = 0; ni < 4; ++ni) {
                acc[mi][ni] = MFMA16(ah[mi], bl[ni], acc[mi][ni]);
                acc[mi][ni] = MFMA16(al[mi], bh[ni], acc[mi][ni]);
                acc[mi][ni] = MFMA16(ah[mi], bh[ni], acc[mi][ni]);
            }
    }

    #pragma unroll
    for (int mi = 0; mi < 2; ++mi)
        #pragma unroll
        for (int ni = 0; ni < 4; ++ni) {
            int col = col0 + wc + ni * 16 + l16;
            float bv = bias ? bias[col] : 0.f;
            #pragma unroll
            for (int r = 0; r < 4; ++r) {
                int row = row0 + wr + mi * 16 + quad * 4 + r;
                C[(size_t)row * N + col] = acc[mi][ni][r] + bv;
            }
        }
}

// ---------------------------------------------------------------------------
// attn_mfma v4: 128-key staged tiles (8 barrier-pairs instead of 16), two
// 64-key passes (QK -> exp2 -> PV) between barriers. bf16 QK + bf16 PV,
// no-max exp2 softmax (log2e in q), l via ones-MFMA (no shuffles).
// LDS: Kh 128x64 + Vt 64x128 (32 KB) + per-wave P (18 KB) = 50 KB
// -> 3 blocks/CU. Grid split-K x2 with add-merge. Accumulation order is
// bit-identical to v3 (same ks2 sequence) - absmax must not move.
// ---------------------------------------------------------------------------
__global__ __launch_bounds__(256) void attn_mfma(
    const __bf16* __restrict__ Qh, const __bf16* __restrict__ Kh,
    const __bf16* __restrict__ Vt,
    float* __restrict__ Opart, float* __restrict__ lpart) {
    const int bh = blockIdx.y;
    const int sp = blockIdx.z;
    const int q0 = blockIdx.x * 128;
    const int w = threadIdx.x >> 6;
    const int lane = threadIdx.x & 63;
    const int l16 = lane & 15, quad = lane >> 4;

    const __bf16* Qhb = Qh + (size_t)bh * Nc * Dc;
    const __bf16* Khb = Kh + (size_t)bh * Nc * Dc;
    const __bf16* Vtb = Vt + (size_t)bh * Dc * Nc;

    bf16x8 qh[2][2];
    #pragma unroll
    for (int mi = 0; mi < 2; ++mi)
        #pragma unroll
        for (int ks = 0; ks < 2; ++ks)
            qh[mi][ks] = *(const bf16x8*)(Qhb
                + (size_t)(q0 + w * 32 + mi * 16 + l16) * Dc + ks * 32 + quad * 8);

    const __bf16 one = (__bf16)1.0f;
    const bf16x8 onesb = {one, one, one, one, one, one, one, one};

    f32x4 Oa[2][4], Ol[2];
    #pragma unroll
    for (int mi = 0; mi < 2; ++mi) {
        #pragma unroll
        for (int ni = 0; ni < 4; ++ni) Oa[mi][ni] = (f32x4){0.f, 0.f, 0.f, 0.f};
        Ol[mi] = (f32x4){0.f, 0.f, 0.f, 0.f};
    }

    __shared__ __bf16 smT[2][8192];       // Kh 128x64, Vt 64x128 (32 KB)
    __shared__ __bf16 Plds[4][32 * 72];   // per-wave P, 64 keys (18 KB)
    __bf16* Pw = Plds[w];

    const int srow = lane & 15;
    const int soct = lane >> 4;

    for (int tile = 0; tile < 8; ++tile) {
        const int kt0 = sp * 1024 + tile * 128;
        __syncthreads();
        // 32 chunks (Kh 16, Vt 16); wave w stages chunks i*4+w
        #pragma unroll
        for (int i = 0; i < 8; ++i) {
            int c = i * 4 + w;             // 0..31
            int arr = c >> 4, t = c & 15;
            const __bf16* src;
            if (arr == 0) {                // Kh: key-group g (16 rows), d-half
                int g = t >> 1, half = t & 1;
                src = Khb + (size_t)(kt0 + 16 * g + srow) * Dc + half * 32 + soct * 8;
            } else {                       // Vt: d-group dg (16 rows), key-quarter kg
                int dg = t >> 2, kg = t & 3;
                src = Vtb + (size_t)(16 * dg + srow) * Nc + kt0 + kg * 32 + soct * 8;
            }
            gload_lds16(src, &smT[arr][t * 512]);
        }
        __syncthreads();

        #pragma unroll
        for (int kp = 0; kp < 2; ++kp) {   // two 64-key passes, no barrier
            f32x4 S[2][4];
            #pragma unroll
            for (int mi = 0; mi < 2; ++mi)
                #pragma unroll
                for (int kt = 0; kt < 4; ++kt) S[mi][kt] = (f32x4){0.f, 0.f, 0.f, 0.f};

            #pragma unroll
            for (int kt = 0; kt < 4; ++kt) {
                int ck = (kp * 4 + kt) * 2;
                int fb = quad * 128 + l16 * 8;
                bf16x8 kh0 = *(const bf16x8*)&smT[0][(ck + 0) * 512 + fb];
                bf16x8 kh1 = *(const bf16x8*)&smT[0][(ck + 1) * 512 + fb];
                #pragma unroll
                for (int mi = 0; mi < 2; ++mi) {
                    S[mi][kt] = MFMA16(qh[mi][0], kh0, S[mi][kt]);
                    S[mi][kt] = MFMA16(qh[mi][1], kh1, S[mi][kt]);
                }
            }

            // p = 2^s; bf16-round; stash for PV (wave-private LDS)
            #pragma unroll
            for (int mi = 0; mi < 2; ++mi)
                #pragma unroll
                for (int kt = 0; kt < 4; ++kt)
                    #pragma unroll
                    for (int r = 0; r < 4; ++r) {
                        float p = EXP2F(S[mi][kt][r]);
                        Pw[(mi * 16 + quad * 4 + r) * 72 + kt * 16 + l16] = (__bf16)p;
                    }

            #pragma unroll
            for (int ks2 = 0; ks2 < 2; ++ks2) {
                int kv = kp * 2 + ks2;     // 32-key quarter within 128-tile
                bf16x8 Pf[2];
                #pragma unroll
                for (int mi = 0; mi < 2; ++mi)
                    Pf[mi] = *(const bf16x8*)&Pw[(mi * 16 + l16) * 72 + ks2 * 32 + quad * 8];
                #pragma unroll
                for (int ni = 0; ni < 4; ++ni) {
                    bf16x8 vf = *(const bf16x8*)
                        &smT[1][(ni * 4 + kv) * 512 + quad * 128 + l16 * 8];
                    #pragma unroll
                    for (int mi = 0; mi < 2; ++mi)
                        Oa[mi][ni] = MFMA16(Pf[mi], vf, Oa[mi][ni]);
                }
                #pragma unroll
                for (int mi = 0; mi < 2; ++mi)   // l += P . 1 (row sums)
                    Ol[mi] = MFMA16(Pf[mi], onesb, Ol[mi]);
            }
        }
    }

    // epilogue: l per-row in Ol (replicated over l16) — no shuffles
    #pragma unroll
    for (int mi = 0; mi < 2; ++mi)
        #pragma unroll
        for (int r = 0; r < 4; ++r) {
            size_t rowg = (size_t)bh * Nc + q0 + w * 32 + mi * 16 + quad * 4 + r;
            if (l16 == 0) lpart[(size_t)sp * 65536 + rowg] = Ol[mi][r];
            #pragma unroll
            for (int ni = 0; ni < 4; ++ni)
                Opart[((size_t)sp * 65536 + rowg) * Dc + ni * 16 + l16] = Oa[mi][ni][r];
        }
}

// ---------------------------------------------------------------------------
// attn_combine: out = (O0+O1)/(l0+l1), scatter to [B][N][H*D], split hi/lo.
// ---------------------------------------------------------------------------
__global__ __launch_bounds__(256) void attn_combine(
    const float* __restrict__ Opart, const float* __restrict__ lpart,
    __bf16* __restrict__ Aoh, __bf16* __restrict__ Aol) {
    const int t = blockIdx.x * 256 + threadIdx.x;
    const int row = t >> 4, c4 = t & 15;
    const int bh = row >> 11, n = row & 2047;
    const int b = bh >> 4, h = bh & 15;

    float4 v0 = ((const float4*)(Opart + (size_t)row * Dc))[c4];
    float4 v1 = ((const float4*)(Opart + ((size_t)65536 + row) * Dc))[c4];
    float inv = 1.f / (lpart[row] + lpart[65536 + row]);
    float e[4] = {(v0.x + v1.x) * inv, (v0.y + v1.y) * inv,
                  (v0.z + v1.z) * inv, (v0.w + v1.w) * inv};
    size_t off = ((size_t)(b * Nc + n)) * Cc + h * Dc + c4 * 4;
    bf16x4 hv, lv;
    #pragma unroll
    for (int i = 0; i < 4; ++i) {
        __bf16 hi = (__bf16)e[i];
        hv[i] = hi;
        lv[i] = (__bf16)(e[i] - (float)hi);
    }
    *(bf16x4*)(Aoh + off) = hv;
    *(bf16x4*)(Aol + off) = lv;
}

// ---------------------------------------------------------------------------
extern "C" void kernel_launch(void* const* d_in, const int* in_sizes, int n_in,
                              void* d_out, int out_size, void* d_ws, size_t ws_size,
                              hipStream_t stream) {
    const float* x      = (const float*)d_in[0];   // (2,2048,1024)
    const float* w_qkv  = (const float*)d_in[1];   // (1024,3072)
    const float* w_proj = (const float*)d_in[2];   // (1024,1024)
    const float* b_proj = (const float*)d_in[3];   // (1024,)
    float* out = (float*)d_out;                    // (2,2048,1024)

    float* cosT = (float*)d_ws;                        //  65,536 f
    float* sinT = cosT + Nc * 32;                      //  65,536 f
    __bf16* bf = (__bf16*)(sinT + Nc * 32);
    constexpr size_t HS = (size_t)Bc * Hc * Nc * Dc;   // 4,194,304
    __bf16* Qh  = bf;                                  // [BH][N][64]
    __bf16* Kh  = Qh + HS;
    __bf16* Vt  = Kh + HS;                             // [BH][64][N]
    __bf16* Xh  = Vt + HS;                             // x bf16 [4096][1024]
    __bf16* Aoh = Xh;                                  //   (reused after qkv GEMM)
    __bf16* Aol = Xh + HS;
    __bf16* Wqh = Aol + HS;                            // w_qkv^T [3072][1024]
    __bf16* Wph = Wqh + (size_t)3072 * 1024;           // w_proj^T hi
    __bf16* Wpl = Wph + (size_t)1024 * 1024;           // w_proj^T lo
    float* Opart = (float*)(Wpl + (size_t)1024 * 1024);  // 2*65536*64 f
    float* lpart = Opart + (size_t)2 * 65536 * Dc;       // 2*65536 f

    // 1. fused prologue: rope tables + all packs (one launch)
    prologue<<<5376, 256, 0, stream>>>(
        x, w_qkv, w_proj, cosT, sinT, Xh, Wqh, Wph, Wpl);

    // 2. fused qkv GEMM (pure bf16) + RoPE(+log2e fold) + V transpose
    gemm_qkv_bf<<<dim3(3072 / 128, 4096 / 128), 256, 0, stream>>>(
        Xh, Wqh, cosT, sinT, Qh, Kh, Vt);

    // 3. MFMA flash attention, split-K x2 -> unnormalized partials
    attn_mfma<<<dim3(Nc / 128, Bc * Hc, 2), 256, 0, stream>>>(
        Qh, Kh, Vt, Opart, lpart);
    attn_combine<<<(65536 * 16) / 256, 256, 0, stream>>>(
        Opart, lpart, Aoh, Aol);

    // 4. out = attn_out @ w_proj + b_proj  (split-bf16, fp32-grade)
    gemm_proj<<<dim3(1024 / 128, 4096 / 64), 256, 0, stream>>>(
        Aoh, Aol, Wph, Wpl, b_proj, out, 4096, 1024, 1024);
}